// Round 8
// baseline (210.438 us; speedup 1.0000x reference)
//
#include <hip/hip_runtime.h>
#include <hip/hip_bf16.h>
#include <math.h>

// ---------------------------------------------------------------------------
// HybridQuantumKernelNet forward, fp32 throughout.
// x[64,3,250,250] -> conv1(6,5x5,s2,p1)+relu -> [64,6,124,124]
//   -> maxpool2 s1 -> pool1 [64,123,123,6] (CHANNEL-LAST)
//   -> conv2(15,3x3,s2,p1)+relu -> [64,15,62,62] -> maxpool2 s1 -> [64,15,61,61]
//   -> flatten K=55815 -> fc1(120)+relu -> fc2(84)+relu -> fc3(1)
//   -> quantum head cos((z-p)/2)^4 @ kh_w + kh_b -> sigmoid -> [p,1-p]
//
// VGPR ladder lessons (r6/r7): __launch_bounds__(256,N) empirically caps
// VGPR at 256/N. N=4 -> 64 VGPR -> catastrophic spill (FETCH 213MB).
// No bound -> 152 VGPR -> only 2 waves/SIMD -> latency-bound (VALUBusy 30%).
// N=2 -> 128 cap: 4 waves/SIMD, live set ~100 fits, no spill. [this round]
// ---------------------------------------------------------------------------

#define KTOT 55815            // 15*61*61
#define KTOT_PAD 55872        // A row stride (alignment only; tail guarded)
#define P1H 123               // pooled1 spatial
#define P2H 61                // pooled2 spatial
#define KC 96                 // fc1 K-chunk
#define NCHUNK 582            // ceil(55815/96)

// ---------------- Kernel 1: conv1 + relu + maxpool(2,s1), channel-last -----
// Tile 16 conv rows x 64 cols; 256 threads = 16 rows x 8 strips x 2 oc-groups
// (og=tid>>7 picks oc {0..2} or {3..5}; x reads shared via L1/L2; all 6
// channels of each output pixel written by THIS block -> no partial lines).
// Per-thread: 8-col strip, 3 oc -> acc[3][8] + r[24] window.
// Even col bases {0,62} => 24-float window starts at mult of 4 => aligned f4.
// LDS cs[6][16][65] = 24.96 KB.
__global__ __launch_bounds__(256, 2) void conv1_pool(
    const float* __restrict__ x, const float* __restrict__ w,
    const float* __restrict__ bias, float* __restrict__ out) {
  __shared__ float cs[6][16][65];
  const int b = blockIdx.y;
  const int ytile = blockIdx.x >> 1, xtile = blockIdx.x & 1;
  const int cy_base = 15 * ytile;                // 0..120
  const int cx_base = xtile ? 62 : 0;            // EVEN
  const int tid = threadIdx.x;
  const int og = __builtin_amdgcn_readfirstlane(tid >> 7);  // wave-uniform
  const int ocb = 3 * og;
  const int ry = (tid >> 3) & 15;                // 0..15 local conv row
  const int tx8 = tid & 7;                       // 8-col strip index
  const int cy = cy_base + ry;
  const int cx0 = cx_base + 8 * tx8;
  const int w0 = 2 * cx0 - 4;                    // window start, mult of 4
  const float* xb = x + b * 187500;

  float acc[3][8];
#pragma unroll
  for (int oc = 0; oc < 3; ++oc) {
    const float bv = bias[ocb + oc];
#pragma unroll
    for (int p = 0; p < 8; ++p) acc[oc][p] = bv;
  }

  const bool cyv = (cy < 124);
#pragma unroll
  for (int ic = 0; ic < 3; ++ic) {
    const float* xc = xb + ic * 62500;
#pragma unroll
    for (int ky = 0; ky < 5; ++ky) {
      const int iy = 2 * cy - 1 + ky;
      const bool vrow = cyv && (iy >= 0) && (iy < 250);
      const float* rp = xc + iy * 250;
      float r[24];
#pragma unroll
      for (int j = 0; j < 6; ++j) {
        const int s = w0 + 4 * j;
        float4 v = {0.f, 0.f, 0.f, 0.f};
        if (vrow) {
          if (s >= 0 && s + 3 < 250) {
            v = *reinterpret_cast<const float4*>(rp + s);
          } else if (s + 3 >= 0 && s < 250) {     // partial edge f4
            v.x = (s + 0 >= 0 && s + 0 < 250) ? rp[s + 0] : 0.f;
            v.y = (s + 1 >= 0 && s + 1 < 250) ? rp[s + 1] : 0.f;
            v.z = (s + 2 >= 0 && s + 2 < 250) ? rp[s + 2] : 0.f;
            v.w = (s + 3 >= 0 && s + 3 < 250) ? rp[s + 3] : 0.f;
          }
        }
        r[4 * j + 0] = v.x; r[4 * j + 1] = v.y;
        r[4 * j + 2] = v.z; r[4 * j + 3] = v.w;
      }
      const float* wp = w + ocb * 75 + ic * 25 + ky * 5;
#pragma unroll
      for (int oc = 0; oc < 3; ++oc)
#pragma unroll
        for (int kx = 0; kx < 5; ++kx) {
          const float wv = wp[oc * 75 + kx];     // wave-uniform (s_load)
#pragma unroll
          for (int p = 0; p < 8; ++p)
            acc[oc][p] = fmaf(r[2 * p + 3 + kx], wv, acc[oc][p]);
        }
    }
  }

#pragma unroll
  for (int oc = 0; oc < 3; ++oc)
#pragma unroll
    for (int p = 0; p < 8; ++p)
      cs[ocb + oc][ry][8 * tx8 + p] = fmaxf(acc[oc][p], 0.f);
  __syncthreads();

  // Pool phase: 15x63 pooled positions per tile, channel-last stores.
  for (int idx = tid; idx < 15 * 63; idx += 256) {
    const int pyl = idx / 63, pxl = idx % 63;
    const int py = cy_base + pyl;
    const int px = cx_base + pxl;
    if (py > 122) continue;
    if (xtile == 1 && (pxl == 0 || px > 122)) continue;
    float* ob = out + ((size_t)(b * P1H + py) * P1H + px) * 6;
    float v[6];
#pragma unroll
    for (int oc = 0; oc < 6; ++oc)
      v[oc] = fmaxf(fmaxf(cs[oc][pyl][pxl],     cs[oc][pyl][pxl + 1]),
                    fmaxf(cs[oc][pyl + 1][pxl], cs[oc][pyl + 1][pxl + 1]));
    float2 o0 = {v[0], v[1]}, o1 = {v[2], v[3]}, o2 = {v[4], v[5]};
    *reinterpret_cast<float2*>(ob + 0) = o0;
    *reinterpret_cast<float2*>(ob + 2) = o1;
    *reinterpret_cast<float2*>(ob + 4) = o2;
  }
}

// ---------------- Kernel 2: conv2 + relu + maxpool(2,s1) fused -------------
// Input channel-last [b][123][123][6]: per tap 6 contiguous floats = 3 f2.
// Output A rows use stride KTOT_PAD (tail handled by fc1 staging guard).
__global__ __launch_bounds__(256, 2) void conv2_pool(
    const float* __restrict__ in, const float* __restrict__ w,
    const float* __restrict__ bias, float* __restrict__ A) {
  __shared__ float cs[15][16][16];
  const int b = blockIdx.y;
  const int ty = blockIdx.x / 5, tx = blockIdx.x % 5;
  const int py0 = ty * 15, px0 = tx * 15;
  const int tid = threadIdx.x;
  const int cyl = tid >> 4, cxl = tid & 15;
  const int cy = py0 + cyl, cx = px0 + cxl;
  const float* ib = in + (size_t)b * (P1H * P1H * 6);
  const bool cv = (cy < 62) && (cx < 62);
  const int iy0 = 2 * cy - 1, ix0 = 2 * cx - 1;

  float rin[54];                                  // layout [ky][kx][ic]
#pragma unroll
  for (int ky = 0; ky < 3; ++ky) {
    const int iy = iy0 + ky;
#pragma unroll
    for (int kx = 0; kx < 3; ++kx) {
      const int ix = ix0 + kx;
      const int e = (ky * 3 + kx) * 6;
      const bool ok = cv && (iy >= 0) && (iy < P1H) && (ix >= 0) && (ix < P1H);
      if (ok) {
        const float* p = ib + ((size_t)iy * P1H + ix) * 6;
        const float2 v0 = *reinterpret_cast<const float2*>(p + 0);
        const float2 v1 = *reinterpret_cast<const float2*>(p + 2);
        const float2 v2 = *reinterpret_cast<const float2*>(p + 4);
        rin[e + 0] = v0.x; rin[e + 1] = v0.y; rin[e + 2] = v1.x;
        rin[e + 3] = v1.y; rin[e + 4] = v2.x; rin[e + 5] = v2.y;
      } else {
        rin[e + 0] = 0.f; rin[e + 1] = 0.f; rin[e + 2] = 0.f;
        rin[e + 3] = 0.f; rin[e + 4] = 0.f; rin[e + 5] = 0.f;
      }
    }
  }
#pragma unroll
  for (int oc = 0; oc < 15; ++oc) {
    float a = bias[oc];
#pragma unroll
    for (int ic = 0; ic < 6; ++ic)
#pragma unroll
      for (int ky = 0; ky < 3; ++ky)
#pragma unroll
        for (int kx = 0; kx < 3; ++kx)
          a = fmaf(rin[(ky * 3 + kx) * 6 + ic],
                   w[oc * 54 + ic * 9 + ky * 3 + kx], a);
    cs[oc][cyl][cxl] = fmaxf(a, 0.f);
  }
  __syncthreads();
  if (tid < 225) {
    const int pyl = tid / 15, pxl = tid % 15;
    const int py = py0 + pyl, px = px0 + pxl;
    if (py < P2H && px < P2H) {
      float* ob = A + (size_t)b * KTOT_PAD;
#pragma unroll
      for (int oc = 0; oc < 15; ++oc) {
        const float v = fmaxf(fmaxf(cs[oc][pyl][pxl], cs[oc][pyl][pxl + 1]),
                              fmaxf(cs[oc][pyl + 1][pxl], cs[oc][pyl + 1][pxl + 1]));
        ob[oc * (P2H * P2H) + py * P2H + px] = v;
      }
    }
  }
}

// ---------------- Kernel 3: fc1 split-K partials, register-tiled -----------
// Block = K-chunk of 96, full 64m x 128n(120 real). 4 waves split n (32 each).
// Lane grid 8mg x 8ng; per-lane tile 8m x 4n. Per k4-step: 8 A-b128 + 4
// W-b128 (XOR-swizzled slots -> conflict-free) feed 128 FMAs.
__global__ __launch_bounds__(256) void fc1_partial(
    const float* __restrict__ A, const float* __restrict__ W,
    float* __restrict__ part) {
  __shared__ float As[64 * KC];
  __shared__ float Ws[128 * KC];
  const int tid = threadIdx.x;
  const int chunk = blockIdx.x;
  const int k0 = chunk * KC;
  const bool full = (k0 + KC <= KTOT);

  for (int idx = tid; idx < 64 * 24; idx += 256) {
    const int m = idx / 24, j = idx % 24;
    const int kg = k0 + 4 * j;
    float4 v;
    if (full || kg + 3 < KTOT) {
      v = *reinterpret_cast<const float4*>(A + (size_t)m * KTOT_PAD + kg);
    } else {
      v.x = (kg + 0 < KTOT) ? A[(size_t)m * KTOT_PAD + kg + 0] : 0.f;
      v.y = (kg + 1 < KTOT) ? A[(size_t)m * KTOT_PAD + kg + 1] : 0.f;
      v.z = (kg + 2 < KTOT) ? A[(size_t)m * KTOT_PAD + kg + 2] : 0.f;
      v.w = (kg + 3 < KTOT) ? A[(size_t)m * KTOT_PAD + kg + 3] : 0.f;
    }
    const int slot = (j & 24) | ((j & 7) ^ ((m >> 3) & 7));
    *reinterpret_cast<float4*>(&As[m * KC + 4 * slot]) = v;
  }
  if (full) {
    for (int idx = tid; idx < 120 * KC; idx += 256) {
      const int n = idx / KC, k = idx - n * KC;
      const int j = k >> 2, q = k & 3;
      const int slot = (j & 24) | ((j & 7) ^ ((n >> 2) & 7));
      Ws[n * KC + 4 * slot + q] = W[(size_t)n * KTOT + k0 + k];
    }
  } else {
    for (int idx = tid; idx < 120 * KC; idx += 256) {
      const int n = idx / KC, k = idx - n * KC;
      const int j = k >> 2, q = k & 3;
      const int slot = (j & 24) | ((j & 7) ^ ((n >> 2) & 7));
      const int kg = k0 + k;
      Ws[n * KC + 4 * slot + q] = (kg < KTOT) ? W[(size_t)n * KTOT + kg] : 0.f;
    }
  }
  __syncthreads();

  const int lane = tid & 63;
  const int wave = __builtin_amdgcn_readfirstlane(tid >> 6);
  const int mg = lane >> 3, ng = lane & 7;
  const int n0 = wave * 32;
  const float* Abase = As + mg * 8 * KC;
  const float* Wbase = Ws + (n0 + ng * 4) * KC;

  float acc[8][4];
#pragma unroll
  for (int r = 0; r < 8; ++r)
#pragma unroll
    for (int s = 0; s < 4; ++s) acc[r][s] = 0.0f;

  for (int k4 = 0; k4 < KC / 4; ++k4) {
    const int sA = 4 * ((k4 & 24) | ((k4 & 7) ^ mg));
    const int sW = 4 * ((k4 & 24) | ((k4 & 7) ^ ng));
    float4 a[8], w[4];
#pragma unroll
    for (int r = 0; r < 8; ++r)
      a[r] = *reinterpret_cast<const float4*>(Abase + r * KC + sA);
#pragma unroll
    for (int s = 0; s < 4; ++s)
      w[s] = *reinterpret_cast<const float4*>(Wbase + s * KC + sW);
#pragma unroll
    for (int r = 0; r < 8; ++r)
#pragma unroll
      for (int s = 0; s < 4; ++s) {
        float t = acc[r][s];
        t = fmaf(a[r].x, w[s].x, t);
        t = fmaf(a[r].y, w[s].y, t);
        t = fmaf(a[r].z, w[s].z, t);
        t = fmaf(a[r].w, w[s].w, t);
        acc[r][s] = t;
      }
  }

  if (n0 + 4 * ng <= 116) {
    float* pb = part + (size_t)chunk * 7680 + n0 + 4 * ng;
#pragma unroll
    for (int r = 0; r < 8; ++r) {
      const float4 v = {acc[r][0], acc[r][1], acc[r][2], acc[r][3]};
      *reinterpret_cast<float4*>(pb + (mg * 8 + r) * 120) = v;
    }
  }
}

// ---------------- Kernel 4: reduce partials + bias + relu ------------------
// 240 blocks x 256: 32 t's per block, 8-way chunk split, LDS combine.
__global__ __launch_bounds__(256) void fc1_reduce(
    const float* __restrict__ part, const float* __restrict__ bias,
    float* __restrict__ h1) {
  __shared__ float red[8][32];
  const int tid = threadIdx.x;
  const int q = tid >> 5, l = tid & 31;
  const int t = blockIdx.x * 32 + l;   // 240*32 = 7680
  float s = 0.0f;
  for (int c = q; c < NCHUNK; c += 8) s += part[(size_t)c * 7680 + t];
  red[q][l] = s;
  __syncthreads();
  if (q == 0) {
    float v = red[0][l] + red[1][l] + red[2][l] + red[3][l] +
              red[4][l] + red[5][l] + red[6][l] + red[7][l] + bias[t % 120];
    h1[t] = fmaxf(v, 0.0f);
  }
}

// ---------------- Kernel 5: fc2 + relu + fc3 + quantum head (merged) -------
// One block. fc2: 4 waves x 21 j-columns each, lane=m, h1 row in LDS.
// h2 kept in LDS; then 64 lanes do fc3 dot + closed-form kernel + sigmoid.
__global__ __launch_bounds__(256) void fc2_final(
    const float* __restrict__ h1, const float* __restrict__ W2,
    const float* __restrict__ b2, const float* __restrict__ w3,
    const float* __restrict__ b3, const float* __restrict__ proto,
    const float* __restrict__ khw, const float* __restrict__ khb,
    float* __restrict__ out) {
  __shared__ float hs[64][121];
  __shared__ float h2s[64][85];
  const int tid = threadIdx.x;
  for (int i = tid; i < 7680; i += 256) hs[i / 120][i % 120] = h1[i];
  __syncthreads();
  const int m = tid & 63;
  const int wv = __builtin_amdgcn_readfirstlane(tid >> 6);
  for (int j = wv; j < 84; j += 4) {
    const float* wj = W2 + j * 120;               // wave-uniform row
    float a = b2[j];
    for (int k = 0; k < 120; ++k) a = fmaf(hs[m][k], wj[k], a);
    h2s[m][j] = fmaxf(a, 0.f);
  }
  __syncthreads();
  if (tid < 64) {
    float z = b3[0];
    for (int k = 0; k < 84; ++k) z = fmaf(h2s[tid][k], w3[k], z);
    float logit = khb[0];
#pragma unroll
    for (int p = 0; p < 10; ++p) {
      const float c = cosf((z - proto[p]) * 0.5f);
      const float c2 = c * c;
      logit = fmaf(c2 * c2, khw[p], logit);
    }
    const float pr = 1.0f / (1.0f + expf(-logit));
    out[tid * 2 + 0] = pr;
    out[tid * 2 + 1] = 1.0f - pr;
  }
}

// ---------------------------------------------------------------------------
extern "C" void kernel_launch(void* const* d_in, const int* in_sizes, int n_in,
                              void* d_out, int out_size, void* d_ws, size_t ws_size,
                              hipStream_t stream) {
  const float* x    = (const float*)d_in[0];
  const float* w1   = (const float*)d_in[1];
  const float* b1   = (const float*)d_in[2];
  const float* w2   = (const float*)d_in[3];
  const float* b2   = (const float*)d_in[4];
  const float* fw1  = (const float*)d_in[5];
  const float* fb1  = (const float*)d_in[6];
  const float* fw2  = (const float*)d_in[7];
  const float* fb2  = (const float*)d_in[8];
  const float* fw3  = (const float*)d_in[9];
  const float* fb3  = (const float*)d_in[10];
  const float* prot = (const float*)d_in[11];
  const float* khw  = (const float*)d_in[12];
  const float* khb  = (const float*)d_in[13];
  float* out = (float*)d_out;

  float* ws = (float*)d_ws;
  // pool1 (dead after conv2) is aliased by fc1 partials (written after).
  float* pool1 = ws;                           // 64*123*123*6 = 5,809,536 f
  float* part  = ws;                           // 582*7680     = 4,469,760 f (alias)
  float* A     = ws + 5809536;                 // 64*55872     = 3,575,808 f
  float* h1    = A + 3575808;                  // 7680 f

  conv1_pool <<<dim3(18, 64), 256, 0, stream>>>(x, w1, b1, pool1);
  conv2_pool <<<dim3(25, 64), 256, 0, stream>>>(pool1, w2, b2, A);
  fc1_partial<<<dim3(NCHUNK), 256, 0, stream>>>(A, fw1, part);
  fc1_reduce <<<dim3(240), 256, 0, stream>>>(part, fb1, h1);
  fc2_final  <<<dim3(1), 256, 0, stream>>>(h1, fw2, fb2, fw3, fb3, prot, khw, khb, out);
}

// Round 9
// 163.736 us; speedup vs baseline: 1.2852x; 1.2852x over previous
//
#include <hip/hip_runtime.h>
#include <hip/hip_bf16.h>
#include <math.h>

// ---------------------------------------------------------------------------
// HybridQuantumKernelNet forward, fp32 throughout.
// x[64,3,250,250] -> conv1(6,5x5,s2,p1)+relu -> [64,6,124,124]
//   -> maxpool2 s1 -> pool1 [64,123,123,6] (CHANNEL-LAST)
//   -> conv2(15,3x3,s2,p1)+relu -> [64,15,62,62] -> maxpool2 s1 -> [64,15,61,61]
//   -> flatten K=55815 -> fc1(120)+relu -> fc2(84)+relu -> fc3(1)
//   -> quantum head cos((z-p)/2)^4 @ kh_w + kh_b -> sigmoid -> [p,1-p]
//
// VGPR ladder lessons (r6-r8): conv1's register-window design has a ~150-reg
// live set. Caps: 64 -> huge spill; 128 -> still ~50MB spill each way;
// natural 152 -> 2 waves/SIMD latency-bound. Fix is structural: stage input
// in LDS (this round) so the live set drops to ~55 regs.
// ---------------------------------------------------------------------------

#define KTOT 55815            // 15*61*61
#define KTOT_PAD 55872        // A row stride (alignment only; tail guarded)
#define P1H 123               // pooled1 spatial
#define P2H 61                // pooled2 spatial
#define KC 96                 // fc1 K-chunk
#define NCHUNK 582            // ceil(55815/96)

// ---------------- Kernel 1: conv1 + relu + maxpool(2,s1), LDS-staged -------
// Tile 16 conv rows x 64 cols. 256 threads = 16 rows x 16 strips(4 cols).
// Per ic: stage 35x136-float input window into xs[35][140] (rows 16B-aligned,
// coalesced f4), then each thread reads an 11-float LDS window per ky and
// does 6oc x 5kx x 4p FMAs. acc[6][4]+r[11] => ~55 live regs, no spill.
// Taps: input local col = 8*st + 2p + 3 + kx  (window staged from
// s0 = 2*cx_base-4, a multiple of 4 => aligned global f4 staging).
__global__ __launch_bounds__(256) void conv1_pool(
    const float* __restrict__ x, const float* __restrict__ w,
    const float* __restrict__ bias, float* __restrict__ out) {
  __shared__ float xs[35][140];                  // 19.6 KB input stage
  __shared__ float cs[6][16][65];                // 25.0 KB conv out tile
  const int b = blockIdx.y;
  const int ytile = blockIdx.x >> 1, xtile = blockIdx.x & 1;
  const int cy_base = 15 * ytile;                // 0..120
  const int cx_base = xtile ? 62 : 0;            // EVEN
  const int tid = threadIdx.x;
  const int ry = tid >> 4;                       // 0..15 local conv row
  const int st = tid & 15;                       // 0..15 strip of 4 cols
  const int gy0 = 2 * cy_base - 1;               // window top row
  const int s0 = 2 * cx_base - 4;                // window left col (mult of 4)
  const float* xb = x + b * 187500;

  float acc[6][4];
#pragma unroll
  for (int oc = 0; oc < 6; ++oc) {
    const float bv = bias[oc];
#pragma unroll
    for (int p = 0; p < 4; ++p) acc[oc][p] = bv;
  }

  for (int ic = 0; ic < 3; ++ic) {
    __syncthreads();                             // xs readers done (ic>0)
    // Stage 35 rows x 34 f4 (136 floats) of channel ic.
    const float* xc = xb + ic * 62500;
    for (int idx = tid; idx < 35 * 34; idx += 256) {
      const int row = idx / 34, j = idx - row * 34;
      const int gy = gy0 + row;
      const int gx = s0 + 4 * j;
      float4 v = {0.f, 0.f, 0.f, 0.f};
      if (gy >= 0 && gy < 250) {
        const float* rp = xc + gy * 250;
        if (gx >= 0 && gx + 3 < 250) {
          v = *reinterpret_cast<const float4*>(rp + gx);
        } else if (gx + 3 >= 0 && gx < 250) {
          v.x = (gx + 0 >= 0 && gx + 0 < 250) ? rp[gx + 0] : 0.f;
          v.y = (gx + 1 >= 0 && gx + 1 < 250) ? rp[gx + 1] : 0.f;
          v.z = (gx + 2 >= 0 && gx + 2 < 250) ? rp[gx + 2] : 0.f;
          v.w = (gx + 3 >= 0 && gx + 3 < 250) ? rp[gx + 3] : 0.f;
        }
      }
      *reinterpret_cast<float4*>(&xs[row][4 * j]) = v;  // 16B-aligned
    }
    __syncthreads();

#pragma unroll
    for (int ky = 0; ky < 5; ++ky) {
      const float* xr = &xs[2 * ry + ky][8 * st];
      float r[11];
#pragma unroll
      for (int o = 0; o < 11; ++o) r[o] = xr[3 + o];
#pragma unroll
      for (int oc = 0; oc < 6; ++oc)
#pragma unroll
        for (int kx = 0; kx < 5; ++kx) {
          const float wv = w[oc * 75 + ic * 25 + ky * 5 + kx];  // s_load
#pragma unroll
          for (int p = 0; p < 4; ++p)
            acc[oc][p] = fmaf(r[2 * p + kx], wv, acc[oc][p]);
        }
    }
  }

#pragma unroll
  for (int oc = 0; oc < 6; ++oc)
#pragma unroll
    for (int p = 0; p < 4; ++p)
      cs[oc][ry][4 * st + p] = fmaxf(acc[oc][p], 0.f);
  __syncthreads();

  // Pool phase: 15x63 pooled positions per tile, channel-last stores.
  for (int idx = tid; idx < 15 * 63; idx += 256) {
    const int pyl = idx / 63, pxl = idx % 63;
    const int py = cy_base + pyl;
    const int px = cx_base + pxl;
    if (py > 122) continue;
    if (xtile == 1 && (pxl == 0 || px > 122)) continue;
    float* ob = out + ((size_t)(b * P1H + py) * P1H + px) * 6;
    float v[6];
#pragma unroll
    for (int oc = 0; oc < 6; ++oc)
      v[oc] = fmaxf(fmaxf(cs[oc][pyl][pxl],     cs[oc][pyl][pxl + 1]),
                    fmaxf(cs[oc][pyl + 1][pxl], cs[oc][pyl + 1][pxl + 1]));
    float2 o0 = {v[0], v[1]}, o1 = {v[2], v[3]}, o2 = {v[4], v[5]};
    *reinterpret_cast<float2*>(ob + 0) = o0;
    *reinterpret_cast<float2*>(ob + 2) = o1;
    *reinterpret_cast<float2*>(ob + 4) = o2;
  }
}

// ---------------- Kernel 2: conv2 + relu + maxpool(2,s1) fused -------------
// Input channel-last [b][123][123][6]: per tap 6 contiguous floats = 3 f2.
// Output A rows use stride KTOT_PAD (tail handled by fc1 staging guard).
__global__ __launch_bounds__(256, 2) void conv2_pool(
    const float* __restrict__ in, const float* __restrict__ w,
    const float* __restrict__ bias, float* __restrict__ A) {
  __shared__ float cs[15][16][16];
  const int b = blockIdx.y;
  const int ty = blockIdx.x / 5, tx = blockIdx.x % 5;
  const int py0 = ty * 15, px0 = tx * 15;
  const int tid = threadIdx.x;
  const int cyl = tid >> 4, cxl = tid & 15;
  const int cy = py0 + cyl, cx = px0 + cxl;
  const float* ib = in + (size_t)b * (P1H * P1H * 6);
  const bool cv = (cy < 62) && (cx < 62);
  const int iy0 = 2 * cy - 1, ix0 = 2 * cx - 1;

  float rin[54];                                  // layout [ky][kx][ic]
#pragma unroll
  for (int ky = 0; ky < 3; ++ky) {
    const int iy = iy0 + ky;
#pragma unroll
    for (int kx = 0; kx < 3; ++kx) {
      const int ix = ix0 + kx;
      const int e = (ky * 3 + kx) * 6;
      const bool ok = cv && (iy >= 0) && (iy < P1H) && (ix >= 0) && (ix < P1H);
      if (ok) {
        const float* p = ib + ((size_t)iy * P1H + ix) * 6;
        const float2 v0 = *reinterpret_cast<const float2*>(p + 0);
        const float2 v1 = *reinterpret_cast<const float2*>(p + 2);
        const float2 v2 = *reinterpret_cast<const float2*>(p + 4);
        rin[e + 0] = v0.x; rin[e + 1] = v0.y; rin[e + 2] = v1.x;
        rin[e + 3] = v1.y; rin[e + 4] = v2.x; rin[e + 5] = v2.y;
      } else {
        rin[e + 0] = 0.f; rin[e + 1] = 0.f; rin[e + 2] = 0.f;
        rin[e + 3] = 0.f; rin[e + 4] = 0.f; rin[e + 5] = 0.f;
      }
    }
  }
#pragma unroll
  for (int oc = 0; oc < 15; ++oc) {
    float a = bias[oc];
#pragma unroll
    for (int ic = 0; ic < 6; ++ic)
#pragma unroll
      for (int ky = 0; ky < 3; ++ky)
#pragma unroll
        for (int kx = 0; kx < 3; ++kx)
          a = fmaf(rin[(ky * 3 + kx) * 6 + ic],
                   w[oc * 54 + ic * 9 + ky * 3 + kx], a);
    cs[oc][cyl][cxl] = fmaxf(a, 0.f);
  }
  __syncthreads();
  if (tid < 225) {
    const int pyl = tid / 15, pxl = tid % 15;
    const int py = py0 + pyl, px = px0 + pxl;
    if (py < P2H && px < P2H) {
      float* ob = A + (size_t)b * KTOT_PAD;
#pragma unroll
      for (int oc = 0; oc < 15; ++oc) {
        const float v = fmaxf(fmaxf(cs[oc][pyl][pxl], cs[oc][pyl][pxl + 1]),
                              fmaxf(cs[oc][pyl + 1][pxl], cs[oc][pyl + 1][pxl + 1]));
        ob[oc * (P2H * P2H) + py * P2H + px] = v;
      }
    }
  }
}

// ---------------- Kernel 3: fc1 split-K partials, register-tiled -----------
// Block = K-chunk of 96, full 64m x 128n(120 real). 4 waves split n (32 each).
// Lane grid 8mg x 8ng; per-lane tile 8m x 4n. Per k4-step: 8 A-b128 + 4
// W-b128 (XOR-swizzled slots -> conflict-free) feed 128 FMAs.
__global__ __launch_bounds__(256) void fc1_partial(
    const float* __restrict__ A, const float* __restrict__ W,
    float* __restrict__ part) {
  __shared__ float As[64 * KC];
  __shared__ float Ws[128 * KC];
  const int tid = threadIdx.x;
  const int chunk = blockIdx.x;
  const int k0 = chunk * KC;
  const bool full = (k0 + KC <= KTOT);

  for (int idx = tid; idx < 64 * 24; idx += 256) {
    const int m = idx / 24, j = idx % 24;
    const int kg = k0 + 4 * j;
    float4 v;
    if (full || kg + 3 < KTOT) {
      v = *reinterpret_cast<const float4*>(A + (size_t)m * KTOT_PAD + kg);
    } else {
      v.x = (kg + 0 < KTOT) ? A[(size_t)m * KTOT_PAD + kg + 0] : 0.f;
      v.y = (kg + 1 < KTOT) ? A[(size_t)m * KTOT_PAD + kg + 1] : 0.f;
      v.z = (kg + 2 < KTOT) ? A[(size_t)m * KTOT_PAD + kg + 2] : 0.f;
      v.w = (kg + 3 < KTOT) ? A[(size_t)m * KTOT_PAD + kg + 3] : 0.f;
    }
    const int slot = (j & 24) | ((j & 7) ^ ((m >> 3) & 7));
    *reinterpret_cast<float4*>(&As[m * KC + 4 * slot]) = v;
  }
  if (full) {
    for (int idx = tid; idx < 120 * KC; idx += 256) {
      const int n = idx / KC, k = idx - n * KC;
      const int j = k >> 2, q = k & 3;
      const int slot = (j & 24) | ((j & 7) ^ ((n >> 2) & 7));
      Ws[n * KC + 4 * slot + q] = W[(size_t)n * KTOT + k0 + k];
    }
  } else {
    for (int idx = tid; idx < 120 * KC; idx += 256) {
      const int n = idx / KC, k = idx - n * KC;
      const int j = k >> 2, q = k & 3;
      const int slot = (j & 24) | ((j & 7) ^ ((n >> 2) & 7));
      const int kg = k0 + k;
      Ws[n * KC + 4 * slot + q] = (kg < KTOT) ? W[(size_t)n * KTOT + kg] : 0.f;
    }
  }
  __syncthreads();

  const int lane = tid & 63;
  const int wave = __builtin_amdgcn_readfirstlane(tid >> 6);
  const int mg = lane >> 3, ng = lane & 7;
  const int n0 = wave * 32;
  const float* Abase = As + mg * 8 * KC;
  const float* Wbase = Ws + (n0 + ng * 4) * KC;

  float acc[8][4];
#pragma unroll
  for (int r = 0; r < 8; ++r)
#pragma unroll
    for (int s = 0; s < 4; ++s) acc[r][s] = 0.0f;

  for (int k4 = 0; k4 < KC / 4; ++k4) {
    const int sA = 4 * ((k4 & 24) | ((k4 & 7) ^ mg));
    const int sW = 4 * ((k4 & 24) | ((k4 & 7) ^ ng));
    float4 a[8], w[4];
#pragma unroll
    for (int r = 0; r < 8; ++r)
      a[r] = *reinterpret_cast<const float4*>(Abase + r * KC + sA);
#pragma unroll
    for (int s = 0; s < 4; ++s)
      w[s] = *reinterpret_cast<const float4*>(Wbase + s * KC + sW);
#pragma unroll
    for (int r = 0; r < 8; ++r)
#pragma unroll
      for (int s = 0; s < 4; ++s) {
        float t = acc[r][s];
        t = fmaf(a[r].x, w[s].x, t);
        t = fmaf(a[r].y, w[s].y, t);
        t = fmaf(a[r].z, w[s].z, t);
        t = fmaf(a[r].w, w[s].w, t);
        acc[r][s] = t;
      }
  }

  if (n0 + 4 * ng <= 116) {
    float* pb = part + (size_t)chunk * 7680 + n0 + 4 * ng;
#pragma unroll
    for (int r = 0; r < 8; ++r) {
      const float4 v = {acc[r][0], acc[r][1], acc[r][2], acc[r][3]};
      *reinterpret_cast<float4*>(pb + (mg * 8 + r) * 120) = v;
    }
  }
}

// ---------------- Kernel 4: reduce partials + bias + relu ------------------
// 240 blocks x 256: 32 t's per block, 8-way chunk split, LDS combine.
__global__ __launch_bounds__(256) void fc1_reduce(
    const float* __restrict__ part, const float* __restrict__ bias,
    float* __restrict__ h1) {
  __shared__ float red[8][32];
  const int tid = threadIdx.x;
  const int q = tid >> 5, l = tid & 31;
  const int t = blockIdx.x * 32 + l;   // 240*32 = 7680
  float s = 0.0f;
  for (int c = q; c < NCHUNK; c += 8) s += part[(size_t)c * 7680 + t];
  red[q][l] = s;
  __syncthreads();
  if (q == 0) {
    float v = red[0][l] + red[1][l] + red[2][l] + red[3][l] +
              red[4][l] + red[5][l] + red[6][l] + red[7][l] + bias[t % 120];
    h1[t] = fmaxf(v, 0.0f);
  }
}

// ---------------- Kernel 5: fc2 + relu + fc3 + quantum head (merged) -------
// One block. fc2: 4 waves x 21 j-columns each, lane=m, h1 row in LDS.
// h2 kept in LDS; then 64 lanes do fc3 dot + closed-form kernel + sigmoid.
__global__ __launch_bounds__(256) void fc2_final(
    const float* __restrict__ h1, const float* __restrict__ W2,
    const float* __restrict__ b2, const float* __restrict__ w3,
    const float* __restrict__ b3, const float* __restrict__ proto,
    const float* __restrict__ khw, const float* __restrict__ khb,
    float* __restrict__ out) {
  __shared__ float hs[64][121];
  __shared__ float h2s[64][85];
  const int tid = threadIdx.x;
  for (int i = tid; i < 7680; i += 256) hs[i / 120][i % 120] = h1[i];
  __syncthreads();
  const int m = tid & 63;
  const int wv = __builtin_amdgcn_readfirstlane(tid >> 6);
  for (int j = wv; j < 84; j += 4) {
    const float* wj = W2 + j * 120;               // wave-uniform row
    float a = b2[j];
    for (int k = 0; k < 120; ++k) a = fmaf(hs[m][k], wj[k], a);
    h2s[m][j] = fmaxf(a, 0.f);
  }
  __syncthreads();
  if (tid < 64) {
    float z = b3[0];
    for (int k = 0; k < 84; ++k) z = fmaf(h2s[tid][k], w3[k], z);
    float logit = khb[0];
#pragma unroll
    for (int p = 0; p < 10; ++p) {
      const float c = cosf((z - proto[p]) * 0.5f);
      const float c2 = c * c;
      logit = fmaf(c2 * c2, khw[p], logit);
    }
    const float pr = 1.0f / (1.0f + expf(-logit));
    out[tid * 2 + 0] = pr;
    out[tid * 2 + 1] = 1.0f - pr;
  }
}

// ---------------------------------------------------------------------------
extern "C" void kernel_launch(void* const* d_in, const int* in_sizes, int n_in,
                              void* d_out, int out_size, void* d_ws, size_t ws_size,
                              hipStream_t stream) {
  const float* x    = (const float*)d_in[0];
  const float* w1   = (const float*)d_in[1];
  const float* b1   = (const float*)d_in[2];
  const float* w2   = (const float*)d_in[3];
  const float* b2   = (const float*)d_in[4];
  const float* fw1  = (const float*)d_in[5];
  const float* fb1  = (const float*)d_in[6];
  const float* fw2  = (const float*)d_in[7];
  const float* fb2  = (const float*)d_in[8];
  const float* fw3  = (const float*)d_in[9];
  const float* fb3  = (const float*)d_in[10];
  const float* prot = (const float*)d_in[11];
  const float* khw  = (const float*)d_in[12];
  const float* khb  = (const float*)d_in[13];
  float* out = (float*)d_out;

  float* ws = (float*)d_ws;
  // pool1 (dead after conv2) is aliased by fc1 partials (written after).
  float* pool1 = ws;                           // 64*123*123*6 = 5,809,536 f
  float* part  = ws;                           // 582*7680     = 4,469,760 f (alias)
  float* A     = ws + 5809536;                 // 64*55872     = 3,575,808 f
  float* h1    = A + 3575808;                  // 7680 f

  conv1_pool <<<dim3(18, 64), 256, 0, stream>>>(x, w1, b1, pool1);
  conv2_pool <<<dim3(25, 64), 256, 0, stream>>>(pool1, w2, b2, A);
  fc1_partial<<<dim3(NCHUNK), 256, 0, stream>>>(A, fw1, part);
  fc1_reduce <<<dim3(240), 256, 0, stream>>>(part, fb1, h1);
  fc2_final  <<<dim3(1), 256, 0, stream>>>(h1, fw2, fb2, fw3, fb3, prot, khw, khb, out);
}

// Round 10
// 144.462 us; speedup vs baseline: 1.4567x; 1.1334x over previous
//
#include <hip/hip_runtime.h>
#include <hip/hip_bf16.h>
#include <math.h>

// ---------------------------------------------------------------------------
// HybridQuantumKernelNet forward, fp32 throughout.
// x[64,3,250,250] -> conv1(6,5x5,s2,p1)+relu -> [64,6,124,124]
//   -> maxpool2 s1 -> pool1 [64,123,123,6] (CHANNEL-LAST)
//   -> conv2(15,3x3,s2,p1)+relu -> [64,15,62,62] -> maxpool2 s1 -> [64,15,61,61]
//   -> flatten K=55815 -> fc1(120)+relu -> fc2(84)+relu -> fc3(1)
//   -> quantum head cos((z-p)/2)^4 @ kh_w + kh_b -> sigmoid -> [p,1-p]
//
// Ladder notes:
//  r6-r8: conv1 register-window design spills at any VGPR cap; LDS-stage it.
//  r9: conv1 LDS-staged scalar reads -> 4-way bank conflicts, LDS-pipe-bound
//      (11 b32 x 1.58 = 101 cy vs 240 FMA cy, x4 SIMDs > FMA wall).
//      fc1_partial 72KB LDS -> ~1 block/CU -> latency-bound at 52us.
//  r10 (this): conv1 reads as 4x ds_read_b128; fc1 KC=64 (47KB LDS, 3 blk/CU).
// ---------------------------------------------------------------------------

#define KTOT 55815            // 15*61*61
#define KTOT_PAD 55872        // A row stride (alignment only; tail guarded)
#define P1H 123               // pooled1 spatial
#define P2H 61                // pooled2 spatial
#define KC 64                 // fc1 K-chunk (per LDS stage)
#define KSPAN 128             // fc1 K per block (2 chunks)
#define NCHUNK 437            // ceil(55815/128)

// ---------------- Kernel 1: conv1 + relu + maxpool(2,s1), LDS-staged -------
// Tile 16 conv rows x 64 cols. 256 threads = 16 rows x 16 strips(4 cols).
// Per ic: stage 35x136 input window into xs[35][140] (16B-aligned rows),
// then per ky each thread does 4x ds_read_b128 (16-float window) feeding
// 6oc x 5kx x 4p = 120 FMAs. b128 cuts LDS-pipe cost ~2x vs 11 scalar reads.
__global__ __launch_bounds__(256) void conv1_pool(
    const float* __restrict__ x, const float* __restrict__ w,
    const float* __restrict__ bias, float* __restrict__ out) {
  __shared__ float xs[35][140];                  // 19.6 KB input stage
  __shared__ float cs[6][16][65];                // 25.0 KB conv out tile
  const int b = blockIdx.y;
  const int ytile = blockIdx.x >> 1, xtile = blockIdx.x & 1;
  const int cy_base = 15 * ytile;                // 0..120
  const int cx_base = xtile ? 62 : 0;            // EVEN
  const int tid = threadIdx.x;
  const int ry = tid >> 4;                       // 0..15 local conv row
  const int st = tid & 15;                       // 0..15 strip of 4 cols
  const int gy0 = 2 * cy_base - 1;               // window top row
  const int s0 = 2 * cx_base - 4;                // window left col (mult of 4)
  const float* xb = x + b * 187500;

  float acc[6][4];
#pragma unroll
  for (int oc = 0; oc < 6; ++oc) {
    const float bv = bias[oc];
#pragma unroll
    for (int p = 0; p < 4; ++p) acc[oc][p] = bv;
  }

  for (int ic = 0; ic < 3; ++ic) {
    __syncthreads();                             // xs readers done (ic>0)
    const float* xc = xb + ic * 62500;
    for (int idx = tid; idx < 35 * 34; idx += 256) {
      const int row = idx / 34, j = idx - row * 34;
      const int gy = gy0 + row;
      const int gx = s0 + 4 * j;
      float4 v = {0.f, 0.f, 0.f, 0.f};
      if (gy >= 0 && gy < 250) {
        const float* rp = xc + gy * 250;
        if (gx >= 0 && gx + 3 < 250) {
          v = *reinterpret_cast<const float4*>(rp + gx);
        } else if (gx + 3 >= 0 && gx < 250) {
          v.x = (gx + 0 >= 0 && gx + 0 < 250) ? rp[gx + 0] : 0.f;
          v.y = (gx + 1 >= 0 && gx + 1 < 250) ? rp[gx + 1] : 0.f;
          v.z = (gx + 2 >= 0 && gx + 2 < 250) ? rp[gx + 2] : 0.f;
          v.w = (gx + 3 >= 0 && gx + 3 < 250) ? rp[gx + 3] : 0.f;
        }
      }
      *reinterpret_cast<float4*>(&xs[row][4 * j]) = v;  // 16B-aligned
    }
    __syncthreads();

#pragma unroll
    for (int ky = 0; ky < 5; ++ky) {
      const float* xr = &xs[2 * ry + ky][8 * st];       // 16B-aligned
      const float4 q0 = *reinterpret_cast<const float4*>(xr + 0);
      const float4 q1 = *reinterpret_cast<const float4*>(xr + 4);
      const float4 q2 = *reinterpret_cast<const float4*>(xr + 8);
      const float4 q3 = *reinterpret_cast<const float4*>(xr + 12);
      const float r16[16] = {q0.x, q0.y, q0.z, q0.w, q1.x, q1.y, q1.z, q1.w,
                             q2.x, q2.y, q2.z, q2.w, q3.x, q3.y, q3.z, q3.w};
#pragma unroll
      for (int oc = 0; oc < 6; ++oc)
#pragma unroll
        for (int kx = 0; kx < 5; ++kx) {
          const float wv = w[oc * 75 + ic * 25 + ky * 5 + kx];  // s_load
#pragma unroll
          for (int p = 0; p < 4; ++p)
            acc[oc][p] = fmaf(r16[2 * p + 3 + kx], wv, acc[oc][p]);
        }
    }
  }

#pragma unroll
  for (int oc = 0; oc < 6; ++oc)
#pragma unroll
    for (int p = 0; p < 4; ++p)
      cs[oc][ry][4 * st + p] = fmaxf(acc[oc][p], 0.f);
  __syncthreads();

  // Pool phase: 15x63 pooled positions per tile, channel-last stores.
  for (int idx = tid; idx < 15 * 63; idx += 256) {
    const int pyl = idx / 63, pxl = idx % 63;
    const int py = cy_base + pyl;
    const int px = cx_base + pxl;
    if (py > 122) continue;
    if (xtile == 1 && (pxl == 0 || px > 122)) continue;
    float* ob = out + ((size_t)(b * P1H + py) * P1H + px) * 6;
    float v[6];
#pragma unroll
    for (int oc = 0; oc < 6; ++oc)
      v[oc] = fmaxf(fmaxf(cs[oc][pyl][pxl],     cs[oc][pyl][pxl + 1]),
                    fmaxf(cs[oc][pyl + 1][pxl], cs[oc][pyl + 1][pxl + 1]));
    float2 o0 = {v[0], v[1]}, o1 = {v[2], v[3]}, o2 = {v[4], v[5]};
    *reinterpret_cast<float2*>(ob + 0) = o0;
    *reinterpret_cast<float2*>(ob + 2) = o1;
    *reinterpret_cast<float2*>(ob + 4) = o2;
  }
}

// ---------------- Kernel 2: conv2 + relu + maxpool(2,s1) fused -------------
// Input channel-last [b][123][123][6]: per tap 6 contiguous floats = 3 f2.
__global__ __launch_bounds__(256, 2) void conv2_pool(
    const float* __restrict__ in, const float* __restrict__ w,
    const float* __restrict__ bias, float* __restrict__ A) {
  __shared__ float cs[15][16][16];
  const int b = blockIdx.y;
  const int ty = blockIdx.x / 5, tx = blockIdx.x % 5;
  const int py0 = ty * 15, px0 = tx * 15;
  const int tid = threadIdx.x;
  const int cyl = tid >> 4, cxl = tid & 15;
  const int cy = py0 + cyl, cx = px0 + cxl;
  const float* ib = in + (size_t)b * (P1H * P1H * 6);
  const bool cv = (cy < 62) && (cx < 62);
  const int iy0 = 2 * cy - 1, ix0 = 2 * cx - 1;

  float rin[54];                                  // layout [ky][kx][ic]
#pragma unroll
  for (int ky = 0; ky < 3; ++ky) {
    const int iy = iy0 + ky;
#pragma unroll
    for (int kx = 0; kx < 3; ++kx) {
      const int ix = ix0 + kx;
      const int e = (ky * 3 + kx) * 6;
      const bool ok = cv && (iy >= 0) && (iy < P1H) && (ix >= 0) && (ix < P1H);
      if (ok) {
        const float* p = ib + ((size_t)iy * P1H + ix) * 6;
        const float2 v0 = *reinterpret_cast<const float2*>(p + 0);
        const float2 v1 = *reinterpret_cast<const float2*>(p + 2);
        const float2 v2 = *reinterpret_cast<const float2*>(p + 4);
        rin[e + 0] = v0.x; rin[e + 1] = v0.y; rin[e + 2] = v1.x;
        rin[e + 3] = v1.y; rin[e + 4] = v2.x; rin[e + 5] = v2.y;
      } else {
        rin[e + 0] = 0.f; rin[e + 1] = 0.f; rin[e + 2] = 0.f;
        rin[e + 3] = 0.f; rin[e + 4] = 0.f; rin[e + 5] = 0.f;
      }
    }
  }
#pragma unroll
  for (int oc = 0; oc < 15; ++oc) {
    float a = bias[oc];
#pragma unroll
    for (int ic = 0; ic < 6; ++ic)
#pragma unroll
      for (int ky = 0; ky < 3; ++ky)
#pragma unroll
        for (int kx = 0; kx < 3; ++kx)
          a = fmaf(rin[(ky * 3 + kx) * 6 + ic],
                   w[oc * 54 + ic * 9 + ky * 3 + kx], a);
    cs[oc][cyl][cxl] = fmaxf(a, 0.f);
  }
  __syncthreads();
  if (tid < 225) {
    const int pyl = tid / 15, pxl = tid % 15;
    const int py = py0 + pyl, px = px0 + pxl;
    if (py < P2H && px < P2H) {
      float* ob = A + (size_t)b * KTOT_PAD;
#pragma unroll
      for (int oc = 0; oc < 15; ++oc) {
        const float v = fmaxf(fmaxf(cs[oc][pyl][pxl], cs[oc][pyl][pxl + 1]),
                              fmaxf(cs[oc][pyl + 1][pxl], cs[oc][pyl + 1][pxl + 1]));
        ob[oc * (P2H * P2H) + py * P2H + px] = v;
      }
    }
  }
}

// ---------------- Kernel 3: fc1 split-K partials, register-tiled -----------
// Block = K-span 128 as 2 sequential LDS chunks of KC=64. LDS 47KB ->
// 3 blocks/CU. Per chunk: stage A[64][16 f4] (aligned f4, KTOT_PAD rows) and
// W[120][16 f4] (scalar, rows unaligned), both XOR-swizzled:
// slot = (j&8)|((j&7)^key), key=mg for A rows (m>>3), key=ng for W (n>>2 &7).
// Reads: a[r] broadcast per-mg, 8 distinct slots -> 32 banks once: clean.
// Per k4-step: 12 b128 feed 128 FMAs per lane (8m x 4n tile).
__global__ __launch_bounds__(256) void fc1_partial(
    const float* __restrict__ A, const float* __restrict__ W,
    float* __restrict__ part) {
  __shared__ float As[64 * KC];                  // 16 KB
  __shared__ float Ws[120 * KC];                 // 30.7 KB
  const int tid = threadIdx.x;
  const int chunk = blockIdx.x;
  const int lane = tid & 63;
  const int wave = __builtin_amdgcn_readfirstlane(tid >> 6);
  const int mg = lane >> 3, ng = lane & 7;
  const int n0 = wave * 32;

  float acc[8][4];
#pragma unroll
  for (int r = 0; r < 8; ++r)
#pragma unroll
    for (int s = 0; s < 4; ++s) acc[r][s] = 0.0f;

  for (int half = 0; half < 2; ++half) {
    const int k0 = chunk * KSPAN + half * KC;
    const bool full = (k0 + KC <= KTOT);
    __syncthreads();                             // prev readers done

    // Stage A: 64 rows x 16 f4; 4 f4 per thread.
    for (int idx = tid; idx < 64 * 16; idx += 256) {
      const int m = idx >> 4, j = idx & 15;
      const int kg = k0 + 4 * j;
      float4 v;
      if (full || kg + 3 < KTOT) {
        v = *reinterpret_cast<const float4*>(A + (size_t)m * KTOT_PAD + kg);
      } else {
        v.x = (kg + 0 < KTOT) ? A[(size_t)m * KTOT_PAD + kg + 0] : 0.f;
        v.y = (kg + 1 < KTOT) ? A[(size_t)m * KTOT_PAD + kg + 1] : 0.f;
        v.z = (kg + 2 < KTOT) ? A[(size_t)m * KTOT_PAD + kg + 2] : 0.f;
        v.w = (kg + 3 < KTOT) ? A[(size_t)m * KTOT_PAD + kg + 3] : 0.f;
      }
      const int slot = (j & 8) | ((j & 7) ^ ((m >> 3) & 7));
      *reinterpret_cast<float4*>(&As[m * KC + 4 * slot]) = v;
    }
    // Stage W: 120x64 scalars (rows unaligned in global), 30 per thread.
    if (full) {
      for (int idx = tid; idx < 120 * KC; idx += 256) {
        const int n = idx >> 6, k = idx & 63;
        const int j = k >> 2, q = k & 3;
        const int slot = (j & 8) | ((j & 7) ^ ((n >> 2) & 7));
        Ws[n * KC + 4 * slot + q] = W[(size_t)n * KTOT + k0 + k];
      }
    } else {
      for (int idx = tid; idx < 120 * KC; idx += 256) {
        const int n = idx >> 6, k = idx & 63;
        const int j = k >> 2, q = k & 3;
        const int slot = (j & 8) | ((j & 7) ^ ((n >> 2) & 7));
        const int kg = k0 + k;
        Ws[n * KC + 4 * slot + q] = (kg < KTOT) ? W[(size_t)n * KTOT + kg] : 0.f;
      }
    }
    __syncthreads();

    const float* Abase = As + mg * 8 * KC;
    const float* Wbase = Ws + (n0 + ng * 4) * KC;
#pragma unroll
    for (int k4 = 0; k4 < KC / 4; ++k4) {
      const int sA = 4 * ((k4 & 8) | ((k4 & 7) ^ mg));
      const int sW = 4 * ((k4 & 8) | ((k4 & 7) ^ ng));
      float4 a[8], wv[4];
#pragma unroll
      for (int r = 0; r < 8; ++r)
        a[r] = *reinterpret_cast<const float4*>(Abase + r * KC + sA);
#pragma unroll
      for (int s = 0; s < 4; ++s)
        wv[s] = *reinterpret_cast<const float4*>(Wbase + s * KC + sW);
#pragma unroll
      for (int r = 0; r < 8; ++r)
#pragma unroll
        for (int s = 0; s < 4; ++s) {
          float t = acc[r][s];
          t = fmaf(a[r].x, wv[s].x, t);
          t = fmaf(a[r].y, wv[s].y, t);
          t = fmaf(a[r].z, wv[s].z, t);
          t = fmaf(a[r].w, wv[s].w, t);
          acc[r][s] = t;
        }
    }
  }

  if (n0 + 4 * ng <= 116) {
    float* pb = part + (size_t)chunk * 7680 + n0 + 4 * ng;
#pragma unroll
    for (int r = 0; r < 8; ++r) {
      const float4 v = {acc[r][0], acc[r][1], acc[r][2], acc[r][3]};
      *reinterpret_cast<float4*>(pb + (mg * 8 + r) * 120) = v;
    }
  }
}

// ---------------- Kernel 4: reduce partials + bias + relu ------------------
// 240 blocks x 256: 32 t's per block, 8-way chunk split, LDS combine.
__global__ __launch_bounds__(256) void fc1_reduce(
    const float* __restrict__ part, const float* __restrict__ bias,
    float* __restrict__ h1) {
  __shared__ float red[8][32];
  const int tid = threadIdx.x;
  const int q = tid >> 5, l = tid & 31;
  const int t = blockIdx.x * 32 + l;   // 240*32 = 7680
  float s = 0.0f;
  for (int c = q; c < NCHUNK; c += 8) s += part[(size_t)c * 7680 + t];
  red[q][l] = s;
  __syncthreads();
  if (q == 0) {
    float v = red[0][l] + red[1][l] + red[2][l] + red[3][l] +
              red[4][l] + red[5][l] + red[6][l] + red[7][l] + bias[t % 120];
    h1[t] = fmaxf(v, 0.0f);
  }
}

// ---------------- Kernel 5: fc2 + relu + fc3 + quantum head (merged) -------
__global__ __launch_bounds__(256) void fc2_final(
    const float* __restrict__ h1, const float* __restrict__ W2,
    const float* __restrict__ b2, const float* __restrict__ w3,
    const float* __restrict__ b3, const float* __restrict__ proto,
    const float* __restrict__ khw, const float* __restrict__ khb,
    float* __restrict__ out) {
  __shared__ float hs[64][121];
  __shared__ float h2s[64][85];
  const int tid = threadIdx.x;
  for (int i = tid; i < 7680; i += 256) hs[i / 120][i % 120] = h1[i];
  __syncthreads();
  const int m = tid & 63;
  const int wv = __builtin_amdgcn_readfirstlane(tid >> 6);
  for (int j = wv; j < 84; j += 4) {
    const float* wj = W2 + j * 120;               // wave-uniform row
    float a = b2[j];
    for (int k = 0; k < 120; ++k) a = fmaf(hs[m][k], wj[k], a);
    h2s[m][j] = fmaxf(a, 0.f);
  }
  __syncthreads();
  if (tid < 64) {
    float z = b3[0];
    for (int k = 0; k < 84; ++k) z = fmaf(h2s[tid][k], w3[k], z);
    float logit = khb[0];
#pragma unroll
    for (int p = 0; p < 10; ++p) {
      const float c = cosf((z - proto[p]) * 0.5f);
      const float c2 = c * c;
      logit = fmaf(c2 * c2, khw[p], logit);
    }
    const float pr = 1.0f / (1.0f + expf(-logit));
    out[tid * 2 + 0] = pr;
    out[tid * 2 + 1] = 1.0f - pr;
  }
}

// ---------------------------------------------------------------------------
extern "C" void kernel_launch(void* const* d_in, const int* in_sizes, int n_in,
                              void* d_out, int out_size, void* d_ws, size_t ws_size,
                              hipStream_t stream) {
  const float* x    = (const float*)d_in[0];
  const float* w1   = (const float*)d_in[1];
  const float* b1   = (const float*)d_in[2];
  const float* w2   = (const float*)d_in[3];
  const float* b2   = (const float*)d_in[4];
  const float* fw1  = (const float*)d_in[5];
  const float* fb1  = (const float*)d_in[6];
  const float* fw2  = (const float*)d_in[7];
  const float* fb2  = (const float*)d_in[8];
  const float* fw3  = (const float*)d_in[9];
  const float* fb3  = (const float*)d_in[10];
  const float* prot = (const float*)d_in[11];
  const float* khw  = (const float*)d_in[12];
  const float* khb  = (const float*)d_in[13];
  float* out = (float*)d_out;

  float* ws = (float*)d_ws;
  // pool1 (dead after conv2) is aliased by fc1 partials (written after).
  float* pool1 = ws;                           // 64*123*123*6 = 5,809,536 f
  float* part  = ws;                           // 437*7680     = 3,356,160 f (alias)
  float* A     = ws + 5809536;                 // 64*55872     = 3,575,808 f
  float* h1    = A + 3575808;                  // 7680 f

  conv1_pool <<<dim3(18, 64), 256, 0, stream>>>(x, w1, b1, pool1);
  conv2_pool <<<dim3(25, 64), 256, 0, stream>>>(pool1, w2, b2, A);
  fc1_partial<<<dim3(NCHUNK), 256, 0, stream>>>(A, fw1, part);
  fc1_reduce <<<dim3(240), 256, 0, stream>>>(part, fb1, h1);
  fc2_final  <<<dim3(1), 256, 0, stream>>>(h1, fw2, fb2, fw3, fb3, prot, khw, khb, out);
}

// Round 11
// 135.238 us; speedup vs baseline: 1.5561x; 1.0682x over previous
//
#include <hip/hip_runtime.h>
#include <hip/hip_bf16.h>
#include <math.h>

// ---------------------------------------------------------------------------
// HybridQuantumKernelNet forward, fp32 throughout.
// x[64,3,250,250] -> conv1(6,5x5,s2,p1)+relu -> [64,6,124,124]
//   -> maxpool2 s1 -> pool1 [64,123,123,6] (CHANNEL-LAST)
//   -> conv2(15,3x3,s2,p1)+relu -> [64,15,62,62] -> maxpool2 s1 -> [64,15,61,61]
//   -> flatten K=55815 -> fc1(120)+relu -> fc2(84)+relu -> fc3(1)
//   -> quantum head cos((z-p)/2)^4 @ kh_w + kh_b -> sigmoid -> [p,1-p]
//
// Ladder notes:
//  r6-r8: conv1 register-window design spills at any VGPR cap -> LDS-stage.
//  r9/r10: LDS reads 2x bank penalty (even-cell aliasing: 64 lanes on 4 of 8
//      bank-groups, 1.1e7 conflicts); stage->barrier->compute serialization
//      at 3 blocks/CU -> VALUBusy 30%.
//  r11 (this): XOR cell swizzle g(c)=c^((c>>3)&1) balances all 8 groups;
//      register-prefetch pipeline hides HBM latency under FMA phase.
// ---------------------------------------------------------------------------

#define KTOT 55815            // 15*61*61
#define KTOT_PAD 55872        // A row stride (alignment only; tail guarded)
#define P1H 123               // pooled1 spatial
#define P2H 61                // pooled2 spatial
#define KC 64                 // fc1 K-chunk (per LDS stage)
#define KSPAN 128             // fc1 K per block (2 chunks)
#define NCHUNK 437            // ceil(55815/128)

// ---------------- Kernel 1: conv1 + relu + maxpool(2,s1), LDS-staged -------
// Tile 16 conv rows x 64 cols. 256 threads = 16 rows x 16 strips(4 cols).
// xs rows = 34 16B-cells, cell c stored at g(c)=c^((c>>3)&1): per-q reads
// then cover all 8 bank-groups evenly (8 lanes each) -> conflict-free.
// Register prefetch rr[5]: ic+1's global loads issued before ic's compute.
__global__ __launch_bounds__(256) void conv1_pool(
    const float* __restrict__ x, const float* __restrict__ w,
    const float* __restrict__ bias, float* __restrict__ out) {
  __shared__ float xs[35][136];                  // 18.6 KB input stage
  __shared__ float cs[6][16][65];                // 25.0 KB conv out tile
  const int b = blockIdx.y;
  const int ytile = blockIdx.x >> 1, xtile = blockIdx.x & 1;
  const int cy_base = 15 * ytile;                // 0..120
  const int cx_base = xtile ? 62 : 0;            // EVEN
  const int tid = threadIdx.x;
  const int ry = tid >> 4;                       // 0..15 local conv row
  const int st = tid & 15;                       // 0..15 strip of 4 cols
  const int gy0 = 2 * cy_base - 1;               // window top row
  const int s0 = 2 * cx_base - 4;                // window left col (mult of 4)
  const float* xb = x + b * 187500;

  float acc[6][4];
#pragma unroll
  for (int oc = 0; oc < 6; ++oc) {
    const float bv = bias[oc];
#pragma unroll
    for (int p = 0; p < 4; ++p) acc[oc][p] = bv;
  }

  float4 rr[5];
  // ---- prefetch ic=0 ----
  {
    const float* xc = xb;
#pragma unroll
    for (int s = 0; s < 5; ++s) {
      const int idx = tid + 256 * s;
      float4 v = {0.f, 0.f, 0.f, 0.f};
      if (idx < 35 * 34) {
        const int row = idx / 34, j = idx - row * 34;
        const int gy = gy0 + row, gx = s0 + 4 * j;
        if (gy >= 0 && gy < 250) {
          const float* rp = xc + gy * 250;
          if (gx >= 0 && gx + 3 < 250) {
            v = *reinterpret_cast<const float4*>(rp + gx);
          } else if (gx + 3 >= 0 && gx < 250) {
            v.x = (gx + 0 >= 0 && gx + 0 < 250) ? rp[gx + 0] : 0.f;
            v.y = (gx + 1 >= 0 && gx + 1 < 250) ? rp[gx + 1] : 0.f;
            v.z = (gx + 2 >= 0 && gx + 2 < 250) ? rp[gx + 2] : 0.f;
            v.w = (gx + 3 >= 0 && gx + 3 < 250) ? rp[gx + 3] : 0.f;
          }
        }
      }
      rr[s] = v;
    }
  }

  for (int ic = 0; ic < 3; ++ic) {
    __syncthreads();                             // xs readers done (ic>0)
    // write prefetched tile (swizzled cells)
#pragma unroll
    for (int s = 0; s < 5; ++s) {
      const int idx = tid + 256 * s;
      if (idx < 35 * 34) {
        const int row = idx / 34, j = idx - row * 34;
        const int gj = j ^ ((j >> 3) & 1);
        *reinterpret_cast<float4*>(&xs[row][4 * gj]) = rr[s];
      }
    }
    __syncthreads();
    // issue next channel's loads now; they land during the FMA phase below
    if (ic < 2) {
      const float* xc = xb + (ic + 1) * 62500;
#pragma unroll
      for (int s = 0; s < 5; ++s) {
        const int idx = tid + 256 * s;
        float4 v = {0.f, 0.f, 0.f, 0.f};
        if (idx < 35 * 34) {
          const int row = idx / 34, j = idx - row * 34;
          const int gy = gy0 + row, gx = s0 + 4 * j;
          if (gy >= 0 && gy < 250) {
            const float* rp = xc + gy * 250;
            if (gx >= 0 && gx + 3 < 250) {
              v = *reinterpret_cast<const float4*>(rp + gx);
            } else if (gx + 3 >= 0 && gx < 250) {
              v.x = (gx + 0 >= 0 && gx + 0 < 250) ? rp[gx + 0] : 0.f;
              v.y = (gx + 1 >= 0 && gx + 1 < 250) ? rp[gx + 1] : 0.f;
              v.z = (gx + 2 >= 0 && gx + 2 < 250) ? rp[gx + 2] : 0.f;
              v.w = (gx + 3 >= 0 && gx + 3 < 250) ? rp[gx + 3] : 0.f;
            }
          }
        }
        rr[s] = v;
      }
    }
    // compute channel ic from xs
#pragma unroll
    for (int ky = 0; ky < 5; ++ky) {
      const int row = 2 * ry + ky;
      float r16[16];
#pragma unroll
      for (int q = 0; q < 4; ++q) {
        const int c = 2 * st + q;
        const int gc = c ^ ((c >> 3) & 1);
        const float4 v = *reinterpret_cast<const float4*>(&xs[row][4 * gc]);
        r16[4 * q + 0] = v.x; r16[4 * q + 1] = v.y;
        r16[4 * q + 2] = v.z; r16[4 * q + 3] = v.w;
      }
#pragma unroll
      for (int oc = 0; oc < 6; ++oc)
#pragma unroll
        for (int kx = 0; kx < 5; ++kx) {
          const float wv = w[oc * 75 + ic * 25 + ky * 5 + kx];  // s_load
#pragma unroll
          for (int p = 0; p < 4; ++p)
            acc[oc][p] = fmaf(r16[2 * p + 3 + kx], wv, acc[oc][p]);
        }
    }
  }

#pragma unroll
  for (int oc = 0; oc < 6; ++oc)
#pragma unroll
    for (int p = 0; p < 4; ++p)
      cs[oc][ry][4 * st + p] = fmaxf(acc[oc][p], 0.f);
  __syncthreads();

  // Pool phase: 15x63 pooled positions per tile, channel-last stores.
  for (int idx = tid; idx < 15 * 63; idx += 256) {
    const int pyl = idx / 63, pxl = idx % 63;
    const int py = cy_base + pyl;
    const int px = cx_base + pxl;
    if (py > 122) continue;
    if (xtile == 1 && (pxl == 0 || px > 122)) continue;
    float* ob = out + ((size_t)(b * P1H + py) * P1H + px) * 6;
    float v[6];
#pragma unroll
    for (int oc = 0; oc < 6; ++oc)
      v[oc] = fmaxf(fmaxf(cs[oc][pyl][pxl],     cs[oc][pyl][pxl + 1]),
                    fmaxf(cs[oc][pyl + 1][pxl], cs[oc][pyl + 1][pxl + 1]));
    float2 o0 = {v[0], v[1]}, o1 = {v[2], v[3]}, o2 = {v[4], v[5]};
    *reinterpret_cast<float2*>(ob + 0) = o0;
    *reinterpret_cast<float2*>(ob + 2) = o1;
    *reinterpret_cast<float2*>(ob + 4) = o2;
  }
}

// ---------------- Kernel 2: conv2 + relu + maxpool(2,s1) fused -------------
// Input channel-last [b][123][123][6]: per tap 6 contiguous floats = 3 f2.
__global__ __launch_bounds__(256, 2) void conv2_pool(
    const float* __restrict__ in, const float* __restrict__ w,
    const float* __restrict__ bias, float* __restrict__ A) {
  __shared__ float cs[15][16][16];
  const int b = blockIdx.y;
  const int ty = blockIdx.x / 5, tx = blockIdx.x % 5;
  const int py0 = ty * 15, px0 = tx * 15;
  const int tid = threadIdx.x;
  const int cyl = tid >> 4, cxl = tid & 15;
  const int cy = py0 + cyl, cx = px0 + cxl;
  const float* ib = in + (size_t)b * (P1H * P1H * 6);
  const bool cv = (cy < 62) && (cx < 62);
  const int iy0 = 2 * cy - 1, ix0 = 2 * cx - 1;

  float rin[54];                                  // layout [ky][kx][ic]
#pragma unroll
  for (int ky = 0; ky < 3; ++ky) {
    const int iy = iy0 + ky;
#pragma unroll
    for (int kx = 0; kx < 3; ++kx) {
      const int ix = ix0 + kx;
      const int e = (ky * 3 + kx) * 6;
      const bool ok = cv && (iy >= 0) && (iy < P1H) && (ix >= 0) && (ix < P1H);
      if (ok) {
        const float* p = ib + ((size_t)iy * P1H + ix) * 6;
        const float2 v0 = *reinterpret_cast<const float2*>(p + 0);
        const float2 v1 = *reinterpret_cast<const float2*>(p + 2);
        const float2 v2 = *reinterpret_cast<const float2*>(p + 4);
        rin[e + 0] = v0.x; rin[e + 1] = v0.y; rin[e + 2] = v1.x;
        rin[e + 3] = v1.y; rin[e + 4] = v2.x; rin[e + 5] = v2.y;
      } else {
        rin[e + 0] = 0.f; rin[e + 1] = 0.f; rin[e + 2] = 0.f;
        rin[e + 3] = 0.f; rin[e + 4] = 0.f; rin[e + 5] = 0.f;
      }
    }
  }
#pragma unroll
  for (int oc = 0; oc < 15; ++oc) {
    float a = bias[oc];
#pragma unroll
    for (int ic = 0; ic < 6; ++ic)
#pragma unroll
      for (int ky = 0; ky < 3; ++ky)
#pragma unroll
        for (int kx = 0; kx < 3; ++kx)
          a = fmaf(rin[(ky * 3 + kx) * 6 + ic],
                   w[oc * 54 + ic * 9 + ky * 3 + kx], a);
    cs[oc][cyl][cxl] = fmaxf(a, 0.f);
  }
  __syncthreads();
  if (tid < 225) {
    const int pyl = tid / 15, pxl = tid % 15;
    const int py = py0 + pyl, px = px0 + pxl;
    if (py < P2H && px < P2H) {
      float* ob = A + (size_t)b * KTOT_PAD;
#pragma unroll
      for (int oc = 0; oc < 15; ++oc) {
        const float v = fmaxf(fmaxf(cs[oc][pyl][pxl], cs[oc][pyl][pxl + 1]),
                              fmaxf(cs[oc][pyl + 1][pxl], cs[oc][pyl + 1][pxl + 1]));
        ob[oc * (P2H * P2H) + py * P2H + px] = v;
      }
    }
  }
}

// ---------------- Kernel 3: fc1 split-K partials, register-tiled -----------
// Block = K-span 128 as 2 sequential LDS chunks of KC=64. LDS 47KB ->
// 3 blocks/CU. XOR-swizzled slots, 8m x 4n per-lane tile, 128 FMA / 12 b128.
__global__ __launch_bounds__(256) void fc1_partial(
    const float* __restrict__ A, const float* __restrict__ W,
    float* __restrict__ part) {
  __shared__ float As[64 * KC];                  // 16 KB
  __shared__ float Ws[120 * KC];                 // 30.7 KB
  const int tid = threadIdx.x;
  const int chunk = blockIdx.x;
  const int lane = tid & 63;
  const int wave = __builtin_amdgcn_readfirstlane(tid >> 6);
  const int mg = lane >> 3, ng = lane & 7;
  const int n0 = wave * 32;

  float acc[8][4];
#pragma unroll
  for (int r = 0; r < 8; ++r)
#pragma unroll
    for (int s = 0; s < 4; ++s) acc[r][s] = 0.0f;

  for (int half = 0; half < 2; ++half) {
    const int k0 = chunk * KSPAN + half * KC;
    const bool full = (k0 + KC <= KTOT);
    __syncthreads();                             // prev readers done

    for (int idx = tid; idx < 64 * 16; idx += 256) {
      const int m = idx >> 4, j = idx & 15;
      const int kg = k0 + 4 * j;
      float4 v;
      if (full || kg + 3 < KTOT) {
        v = *reinterpret_cast<const float4*>(A + (size_t)m * KTOT_PAD + kg);
      } else {
        v.x = (kg + 0 < KTOT) ? A[(size_t)m * KTOT_PAD + kg + 0] : 0.f;
        v.y = (kg + 1 < KTOT) ? A[(size_t)m * KTOT_PAD + kg + 1] : 0.f;
        v.z = (kg + 2 < KTOT) ? A[(size_t)m * KTOT_PAD + kg + 2] : 0.f;
        v.w = (kg + 3 < KTOT) ? A[(size_t)m * KTOT_PAD + kg + 3] : 0.f;
      }
      const int slot = (j & 8) | ((j & 7) ^ ((m >> 3) & 7));
      *reinterpret_cast<float4*>(&As[m * KC + 4 * slot]) = v;
    }
    if (full) {
      for (int idx = tid; idx < 120 * KC; idx += 256) {
        const int n = idx >> 6, k = idx & 63;
        const int j = k >> 2, q = k & 3;
        const int slot = (j & 8) | ((j & 7) ^ ((n >> 2) & 7));
        Ws[n * KC + 4 * slot + q] = W[(size_t)n * KTOT + k0 + k];
      }
    } else {
      for (int idx = tid; idx < 120 * KC; idx += 256) {
        const int n = idx >> 6, k = idx & 63;
        const int j = k >> 2, q = k & 3;
        const int slot = (j & 8) | ((j & 7) ^ ((n >> 2) & 7));
        const int kg = k0 + k;
        Ws[n * KC + 4 * slot + q] = (kg < KTOT) ? W[(size_t)n * KTOT + kg] : 0.f;
      }
    }
    __syncthreads();

    const float* Abase = As + mg * 8 * KC;
    const float* Wbase = Ws + (n0 + ng * 4) * KC;
#pragma unroll
    for (int k4 = 0; k4 < KC / 4; ++k4) {
      const int sA = 4 * ((k4 & 8) | ((k4 & 7) ^ mg));
      const int sW = 4 * ((k4 & 8) | ((k4 & 7) ^ ng));
      float4 a[8], wv[4];
#pragma unroll
      for (int r = 0; r < 8; ++r)
        a[r] = *reinterpret_cast<const float4*>(Abase + r * KC + sA);
#pragma unroll
      for (int s = 0; s < 4; ++s)
        wv[s] = *reinterpret_cast<const float4*>(Wbase + s * KC + sW);
#pragma unroll
      for (int r = 0; r < 8; ++r)
#pragma unroll
        for (int s = 0; s < 4; ++s) {
          float t = acc[r][s];
          t = fmaf(a[r].x, wv[s].x, t);
          t = fmaf(a[r].y, wv[s].y, t);
          t = fmaf(a[r].z, wv[s].z, t);
          t = fmaf(a[r].w, wv[s].w, t);
          acc[r][s] = t;
        }
    }
  }

  if (n0 + 4 * ng <= 116) {
    float* pb = part + (size_t)chunk * 7680 + n0 + 4 * ng;
#pragma unroll
    for (int r = 0; r < 8; ++r) {
      const float4 v = {acc[r][0], acc[r][1], acc[r][2], acc[r][3]};
      *reinterpret_cast<float4*>(pb + (mg * 8 + r) * 120) = v;
    }
  }
}

// ---------------- Kernel 4: reduce partials + bias + relu ------------------
__global__ __launch_bounds__(256) void fc1_reduce(
    const float* __restrict__ part, const float* __restrict__ bias,
    float* __restrict__ h1) {
  __shared__ float red[8][32];
  const int tid = threadIdx.x;
  const int q = tid >> 5, l = tid & 31;
  const int t = blockIdx.x * 32 + l;   // 240*32 = 7680
  float s = 0.0f;
  for (int c = q; c < NCHUNK; c += 8) s += part[(size_t)c * 7680 + t];
  red[q][l] = s;
  __syncthreads();
  if (q == 0) {
    float v = red[0][l] + red[1][l] + red[2][l] + red[3][l] +
              red[4][l] + red[5][l] + red[6][l] + red[7][l] + bias[t % 120];
    h1[t] = fmaxf(v, 0.0f);
  }
}

// ---------------- Kernel 5: fc2 + relu + fc3 + quantum head (merged) -------
__global__ __launch_bounds__(256) void fc2_final(
    const float* __restrict__ h1, const float* __restrict__ W2,
    const float* __restrict__ b2, const float* __restrict__ w3,
    const float* __restrict__ b3, const float* __restrict__ proto,
    const float* __restrict__ khw, const float* __restrict__ khb,
    float* __restrict__ out) {
  __shared__ float hs[64][121];
  __shared__ float h2s[64][85];
  const int tid = threadIdx.x;
  for (int i = tid; i < 7680; i += 256) hs[i / 120][i % 120] = h1[i];
  __syncthreads();
  const int m = tid & 63;
  const int wv = __builtin_amdgcn_readfirstlane(tid >> 6);
  for (int j = wv; j < 84; j += 4) {
    const float* wj = W2 + j * 120;               // wave-uniform row
    float a = b2[j];
    for (int k = 0; k < 120; ++k) a = fmaf(hs[m][k], wj[k], a);
    h2s[m][j] = fmaxf(a, 0.f);
  }
  __syncthreads();
  if (tid < 64) {
    float z = b3[0];
    for (int k = 0; k < 84; ++k) z = fmaf(h2s[tid][k], w3[k], z);
    float logit = khb[0];
#pragma unroll
    for (int p = 0; p < 10; ++p) {
      const float c = cosf((z - proto[p]) * 0.5f);
      const float c2 = c * c;
      logit = fmaf(c2 * c2, khw[p], logit);
    }
    const float pr = 1.0f / (1.0f + expf(-logit));
    out[tid * 2 + 0] = pr;
    out[tid * 2 + 1] = 1.0f - pr;
  }
}

// ---------------------------------------------------------------------------
extern "C" void kernel_launch(void* const* d_in, const int* in_sizes, int n_in,
                              void* d_out, int out_size, void* d_ws, size_t ws_size,
                              hipStream_t stream) {
  const float* x    = (const float*)d_in[0];
  const float* w1   = (const float*)d_in[1];
  const float* b1   = (const float*)d_in[2];
  const float* w2   = (const float*)d_in[3];
  const float* b2   = (const float*)d_in[4];
  const float* fw1  = (const float*)d_in[5];
  const float* fb1  = (const float*)d_in[6];
  const float* fw2  = (const float*)d_in[7];
  const float* fb2  = (const float*)d_in[8];
  const float* fw3  = (const float*)d_in[9];
  const float* fb3  = (const float*)d_in[10];
  const float* prot = (const float*)d_in[11];
  const float* khw  = (const float*)d_in[12];
  const float* khb  = (const float*)d_in[13];
  float* out = (float*)d_out;

  float* ws = (float*)d_ws;
  // pool1 (dead after conv2) is aliased by fc1 partials (written after).
  float* pool1 = ws;                           // 64*123*123*6 = 5,809,536 f
  float* part  = ws;                           // 437*7680     = 3,356,160 f (alias)
  float* A     = ws + 5809536;                 // 64*55872     = 3,575,808 f
  float* h1    = A + 3575808;                  // 7680 f

  conv1_pool <<<dim3(18, 64), 256, 0, stream>>>(x, w1, b1, pool1);
  conv2_pool <<<dim3(25, 64), 256, 0, stream>>>(pool1, w2, b2, A);
  fc1_partial<<<dim3(NCHUNK), 256, 0, stream>>>(A, fw1, part);
  fc1_reduce <<<dim3(240), 256, 0, stream>>>(part, fb1, h1);
  fc2_final  <<<dim3(1), 256, 0, stream>>>(h1, fw2, fb2, fw3, fb3, prot, khw, khb, out);
}

// Round 12
// 111.262 us; speedup vs baseline: 1.8914x; 1.2155x over previous
//
#include <hip/hip_runtime.h>
#include <hip/hip_bf16.h>
#include <math.h>

// ---------------------------------------------------------------------------
// HybridQuantumKernelNet forward, fp32 throughout.
// x[64,3,250,250] -> conv1(6,5x5,s2,p1)+relu -> [64,6,124,124]
//   -> maxpool2 s1 -> pool1 [64,123,123,6] (CHANNEL-LAST)
//   -> conv2(15,3x3,s2,p1)+relu -> [64,15,62,62] -> maxpool2 s1 -> [64,15,61,61]
//   -> flatten K=55815 -> fc1(120)+relu -> fc2(84)+relu -> fc3(1)
//   -> quantum head cos((z-p)/2)^4 @ kh_w + kh_b -> sigmoid -> [p,1-p]
//
// Ladder notes:
//  r6-r8: conv1 register-window design spills at any VGPR cap -> LDS-stage.
//  r9/r10: conv1 LDS 2x bank penalty + barrier serialization -> r11 XOR
//      swizzle + register prefetch (worked; conv1 out of top-5).
//  r11: merged fc2_final = 1 block = 51us serial chain. r12 (this): un-merge
//      back to fc2_kernel (21 blocks, 1 column/wave) + final_kernel.
// ---------------------------------------------------------------------------

#define KTOT 55815            // 15*61*61
#define KTOT_PAD 55872        // A row stride (alignment only; tail guarded)
#define P1H 123               // pooled1 spatial
#define P2H 61                // pooled2 spatial
#define KC 64                 // fc1 K-chunk (per LDS stage)
#define KSPAN 128             // fc1 K per block (2 chunks)
#define NCHUNK 437            // ceil(55815/128)

// ---------------- Kernel 1: conv1 + relu + maxpool(2,s1), LDS-staged -------
// Tile 16 conv rows x 64 cols. 256 threads = 16 rows x 16 strips(4 cols).
// xs rows = 34 16B-cells, cell c stored at g(c)=c^((c>>3)&1): per-q reads
// cover all 8 bank-groups evenly -> conflict-free. Register prefetch rr[5]:
// ic+1's global loads issued before ic's compute (hide HBM under FMAs).
__global__ __launch_bounds__(256) void conv1_pool(
    const float* __restrict__ x, const float* __restrict__ w,
    const float* __restrict__ bias, float* __restrict__ out) {
  __shared__ float xs[35][136];                  // 18.6 KB input stage
  __shared__ float cs[6][16][65];                // 25.0 KB conv out tile
  const int b = blockIdx.y;
  const int ytile = blockIdx.x >> 1, xtile = blockIdx.x & 1;
  const int cy_base = 15 * ytile;                // 0..120
  const int cx_base = xtile ? 62 : 0;            // EVEN
  const int tid = threadIdx.x;
  const int ry = tid >> 4;                       // 0..15 local conv row
  const int st = tid & 15;                       // 0..15 strip of 4 cols
  const int gy0 = 2 * cy_base - 1;               // window top row
  const int s0 = 2 * cx_base - 4;                // window left col (mult of 4)
  const float* xb = x + b * 187500;

  float acc[6][4];
#pragma unroll
  for (int oc = 0; oc < 6; ++oc) {
    const float bv = bias[oc];
#pragma unroll
    for (int p = 0; p < 4; ++p) acc[oc][p] = bv;
  }

  float4 rr[5];
  {
    const float* xc = xb;
#pragma unroll
    for (int s = 0; s < 5; ++s) {
      const int idx = tid + 256 * s;
      float4 v = {0.f, 0.f, 0.f, 0.f};
      if (idx < 35 * 34) {
        const int row = idx / 34, j = idx - row * 34;
        const int gy = gy0 + row, gx = s0 + 4 * j;
        if (gy >= 0 && gy < 250) {
          const float* rp = xc + gy * 250;
          if (gx >= 0 && gx + 3 < 250) {
            v = *reinterpret_cast<const float4*>(rp + gx);
          } else if (gx + 3 >= 0 && gx < 250) {
            v.x = (gx + 0 >= 0 && gx + 0 < 250) ? rp[gx + 0] : 0.f;
            v.y = (gx + 1 >= 0 && gx + 1 < 250) ? rp[gx + 1] : 0.f;
            v.z = (gx + 2 >= 0 && gx + 2 < 250) ? rp[gx + 2] : 0.f;
            v.w = (gx + 3 >= 0 && gx + 3 < 250) ? rp[gx + 3] : 0.f;
          }
        }
      }
      rr[s] = v;
    }
  }

  for (int ic = 0; ic < 3; ++ic) {
    __syncthreads();                             // xs readers done (ic>0)
#pragma unroll
    for (int s = 0; s < 5; ++s) {
      const int idx = tid + 256 * s;
      if (idx < 35 * 34) {
        const int row = idx / 34, j = idx - row * 34;
        const int gj = j ^ ((j >> 3) & 1);
        *reinterpret_cast<float4*>(&xs[row][4 * gj]) = rr[s];
      }
    }
    __syncthreads();
    if (ic < 2) {
      const float* xc = xb + (ic + 1) * 62500;
#pragma unroll
      for (int s = 0; s < 5; ++s) {
        const int idx = tid + 256 * s;
        float4 v = {0.f, 0.f, 0.f, 0.f};
        if (idx < 35 * 34) {
          const int row = idx / 34, j = idx - row * 34;
          const int gy = gy0 + row, gx = s0 + 4 * j;
          if (gy >= 0 && gy < 250) {
            const float* rp = xc + gy * 250;
            if (gx >= 0 && gx + 3 < 250) {
              v = *reinterpret_cast<const float4*>(rp + gx);
            } else if (gx + 3 >= 0 && gx < 250) {
              v.x = (gx + 0 >= 0 && gx + 0 < 250) ? rp[gx + 0] : 0.f;
              v.y = (gx + 1 >= 0 && gx + 1 < 250) ? rp[gx + 1] : 0.f;
              v.z = (gx + 2 >= 0 && gx + 2 < 250) ? rp[gx + 2] : 0.f;
              v.w = (gx + 3 >= 0 && gx + 3 < 250) ? rp[gx + 3] : 0.f;
            }
          }
        }
        rr[s] = v;
      }
    }
#pragma unroll
    for (int ky = 0; ky < 5; ++ky) {
      const int row = 2 * ry + ky;
      float r16[16];
#pragma unroll
      for (int q = 0; q < 4; ++q) {
        const int c = 2 * st + q;
        const int gc = c ^ ((c >> 3) & 1);
        const float4 v = *reinterpret_cast<const float4*>(&xs[row][4 * gc]);
        r16[4 * q + 0] = v.x; r16[4 * q + 1] = v.y;
        r16[4 * q + 2] = v.z; r16[4 * q + 3] = v.w;
      }
#pragma unroll
      for (int oc = 0; oc < 6; ++oc)
#pragma unroll
        for (int kx = 0; kx < 5; ++kx) {
          const float wv = w[oc * 75 + ic * 25 + ky * 5 + kx];  // s_load
#pragma unroll
          for (int p = 0; p < 4; ++p)
            acc[oc][p] = fmaf(r16[2 * p + 3 + kx], wv, acc[oc][p]);
        }
    }
  }

#pragma unroll
  for (int oc = 0; oc < 6; ++oc)
#pragma unroll
    for (int p = 0; p < 4; ++p)
      cs[oc][ry][4 * st + p] = fmaxf(acc[oc][p], 0.f);
  __syncthreads();

  for (int idx = tid; idx < 15 * 63; idx += 256) {
    const int pyl = idx / 63, pxl = idx % 63;
    const int py = cy_base + pyl;
    const int px = cx_base + pxl;
    if (py > 122) continue;
    if (xtile == 1 && (pxl == 0 || px > 122)) continue;
    float* ob = out + ((size_t)(b * P1H + py) * P1H + px) * 6;
    float v[6];
#pragma unroll
    for (int oc = 0; oc < 6; ++oc)
      v[oc] = fmaxf(fmaxf(cs[oc][pyl][pxl],     cs[oc][pyl][pxl + 1]),
                    fmaxf(cs[oc][pyl + 1][pxl], cs[oc][pyl + 1][pxl + 1]));
    float2 o0 = {v[0], v[1]}, o1 = {v[2], v[3]}, o2 = {v[4], v[5]};
    *reinterpret_cast<float2*>(ob + 0) = o0;
    *reinterpret_cast<float2*>(ob + 2) = o1;
    *reinterpret_cast<float2*>(ob + 4) = o2;
  }
}

// ---------------- Kernel 2: conv2 + relu + maxpool(2,s1) fused -------------
__global__ __launch_bounds__(256, 2) void conv2_pool(
    const float* __restrict__ in, const float* __restrict__ w,
    const float* __restrict__ bias, float* __restrict__ A) {
  __shared__ float cs[15][16][16];
  const int b = blockIdx.y;
  const int ty = blockIdx.x / 5, tx = blockIdx.x % 5;
  const int py0 = ty * 15, px0 = tx * 15;
  const int tid = threadIdx.x;
  const int cyl = tid >> 4, cxl = tid & 15;
  const int cy = py0 + cyl, cx = px0 + cxl;
  const float* ib = in + (size_t)b * (P1H * P1H * 6);
  const bool cv = (cy < 62) && (cx < 62);
  const int iy0 = 2 * cy - 1, ix0 = 2 * cx - 1;

  float rin[54];                                  // layout [ky][kx][ic]
#pragma unroll
  for (int ky = 0; ky < 3; ++ky) {
    const int iy = iy0 + ky;
#pragma unroll
    for (int kx = 0; kx < 3; ++kx) {
      const int ix = ix0 + kx;
      const int e = (ky * 3 + kx) * 6;
      const bool ok = cv && (iy >= 0) && (iy < P1H) && (ix >= 0) && (ix < P1H);
      if (ok) {
        const float* p = ib + ((size_t)iy * P1H + ix) * 6;
        const float2 v0 = *reinterpret_cast<const float2*>(p + 0);
        const float2 v1 = *reinterpret_cast<const float2*>(p + 2);
        const float2 v2 = *reinterpret_cast<const float2*>(p + 4);
        rin[e + 0] = v0.x; rin[e + 1] = v0.y; rin[e + 2] = v1.x;
        rin[e + 3] = v1.y; rin[e + 4] = v2.x; rin[e + 5] = v2.y;
      } else {
        rin[e + 0] = 0.f; rin[e + 1] = 0.f; rin[e + 2] = 0.f;
        rin[e + 3] = 0.f; rin[e + 4] = 0.f; rin[e + 5] = 0.f;
      }
    }
  }
#pragma unroll
  for (int oc = 0; oc < 15; ++oc) {
    float a = bias[oc];
#pragma unroll
    for (int ic = 0; ic < 6; ++ic)
#pragma unroll
      for (int ky = 0; ky < 3; ++ky)
#pragma unroll
        for (int kx = 0; kx < 3; ++kx)
          a = fmaf(rin[(ky * 3 + kx) * 6 + ic],
                   w[oc * 54 + ic * 9 + ky * 3 + kx], a);
    cs[oc][cyl][cxl] = fmaxf(a, 0.f);
  }
  __syncthreads();
  if (tid < 225) {
    const int pyl = tid / 15, pxl = tid % 15;
    const int py = py0 + pyl, px = px0 + pxl;
    if (py < P2H && px < P2H) {
      float* ob = A + (size_t)b * KTOT_PAD;
#pragma unroll
      for (int oc = 0; oc < 15; ++oc) {
        const float v = fmaxf(fmaxf(cs[oc][pyl][pxl], cs[oc][pyl][pxl + 1]),
                              fmaxf(cs[oc][pyl + 1][pxl], cs[oc][pyl + 1][pxl + 1]));
        ob[oc * (P2H * P2H) + py * P2H + px] = v;
      }
    }
  }
}

// ---------------- Kernel 3: fc1 split-K partials, register-tiled -----------
__global__ __launch_bounds__(256) void fc1_partial(
    const float* __restrict__ A, const float* __restrict__ W,
    float* __restrict__ part) {
  __shared__ float As[64 * KC];                  // 16 KB
  __shared__ float Ws[120 * KC];                 // 30.7 KB
  const int tid = threadIdx.x;
  const int chunk = blockIdx.x;
  const int lane = tid & 63;
  const int wave = __builtin_amdgcn_readfirstlane(tid >> 6);
  const int mg = lane >> 3, ng = lane & 7;
  const int n0 = wave * 32;

  float acc[8][4];
#pragma unroll
  for (int r = 0; r < 8; ++r)
#pragma unroll
    for (int s = 0; s < 4; ++s) acc[r][s] = 0.0f;

  for (int half = 0; half < 2; ++half) {
    const int k0 = chunk * KSPAN + half * KC;
    const bool full = (k0 + KC <= KTOT);
    __syncthreads();                             // prev readers done

    for (int idx = tid; idx < 64 * 16; idx += 256) {
      const int m = idx >> 4, j = idx & 15;
      const int kg = k0 + 4 * j;
      float4 v;
      if (full || kg + 3 < KTOT) {
        v = *reinterpret_cast<const float4*>(A + (size_t)m * KTOT_PAD + kg);
      } else {
        v.x = (kg + 0 < KTOT) ? A[(size_t)m * KTOT_PAD + kg + 0] : 0.f;
        v.y = (kg + 1 < KTOT) ? A[(size_t)m * KTOT_PAD + kg + 1] : 0.f;
        v.z = (kg + 2 < KTOT) ? A[(size_t)m * KTOT_PAD + kg + 2] : 0.f;
        v.w = (kg + 3 < KTOT) ? A[(size_t)m * KTOT_PAD + kg + 3] : 0.f;
      }
      const int slot = (j & 8) | ((j & 7) ^ ((m >> 3) & 7));
      *reinterpret_cast<float4*>(&As[m * KC + 4 * slot]) = v;
    }
    if (full) {
      for (int idx = tid; idx < 120 * KC; idx += 256) {
        const int n = idx >> 6, k = idx & 63;
        const int j = k >> 2, q = k & 3;
        const int slot = (j & 8) | ((j & 7) ^ ((n >> 2) & 7));
        Ws[n * KC + 4 * slot + q] = W[(size_t)n * KTOT + k0 + k];
      }
    } else {
      for (int idx = tid; idx < 120 * KC; idx += 256) {
        const int n = idx >> 6, k = idx & 63;
        const int j = k >> 2, q = k & 3;
        const int slot = (j & 8) | ((j & 7) ^ ((n >> 2) & 7));
        const int kg = k0 + k;
        Ws[n * KC + 4 * slot + q] = (kg < KTOT) ? W[(size_t)n * KTOT + kg] : 0.f;
      }
    }
    __syncthreads();

    const float* Abase = As + mg * 8 * KC;
    const float* Wbase = Ws + (n0 + ng * 4) * KC;
#pragma unroll
    for (int k4 = 0; k4 < KC / 4; ++k4) {
      const int sA = 4 * ((k4 & 8) | ((k4 & 7) ^ mg));
      const int sW = 4 * ((k4 & 8) | ((k4 & 7) ^ ng));
      float4 a[8], wv[4];
#pragma unroll
      for (int r = 0; r < 8; ++r)
        a[r] = *reinterpret_cast<const float4*>(Abase + r * KC + sA);
#pragma unroll
      for (int s = 0; s < 4; ++s)
        wv[s] = *reinterpret_cast<const float4*>(Wbase + s * KC + sW);
#pragma unroll
      for (int r = 0; r < 8; ++r)
#pragma unroll
        for (int s = 0; s < 4; ++s) {
          float t = acc[r][s];
          t = fmaf(a[r].x, wv[s].x, t);
          t = fmaf(a[r].y, wv[s].y, t);
          t = fmaf(a[r].z, wv[s].z, t);
          t = fmaf(a[r].w, wv[s].w, t);
          acc[r][s] = t;
        }
    }
  }

  if (n0 + 4 * ng <= 116) {
    float* pb = part + (size_t)chunk * 7680 + n0 + 4 * ng;
#pragma unroll
    for (int r = 0; r < 8; ++r) {
      const float4 v = {acc[r][0], acc[r][1], acc[r][2], acc[r][3]};
      *reinterpret_cast<float4*>(pb + (mg * 8 + r) * 120) = v;
    }
  }
}

// ---------------- Kernel 4: reduce partials + bias + relu ------------------
__global__ __launch_bounds__(256) void fc1_reduce(
    const float* __restrict__ part, const float* __restrict__ bias,
    float* __restrict__ h1) {
  __shared__ float red[8][32];
  const int tid = threadIdx.x;
  const int q = tid >> 5, l = tid & 31;
  const int t = blockIdx.x * 32 + l;   // 240*32 = 7680
  float s = 0.0f;
  for (int c = q; c < NCHUNK; c += 8) s += part[(size_t)c * 7680 + t];
  red[q][l] = s;
  __syncthreads();
  if (q == 0) {
    float v = red[0][l] + red[1][l] + red[2][l] + red[3][l] +
              red[4][l] + red[5][l] + red[6][l] + red[7][l] + bias[t % 120];
    h1[t] = fmaxf(v, 0.0f);
  }
}

// ---------------- Kernel 5: fc2 + relu (21 blocks, 1 column/wave) ----------
__global__ __launch_bounds__(256) void fc2_kernel(
    const float* __restrict__ h1, const float* __restrict__ W,
    const float* __restrict__ bias, float* __restrict__ h2) {
  __shared__ float hs[64][121];
  const int tid = threadIdx.x;
  for (int i = tid; i < 7680; i += 256) hs[i / 120][i % 120] = h1[i];
  __syncthreads();
  const int m = tid & 63;
  const int j = blockIdx.x * 4 + __builtin_amdgcn_readfirstlane(tid >> 6);
  const float* wj = W + j * 120;
  float a = bias[j];
  for (int k = 0; k < 120; ++k) a = fmaf(hs[m][k], wj[k], a);
  h2[m * 84 + j] = fmaxf(a, 0.0f);
}

// ---------------- Kernel 6: fc3 + quantum kernel head + sigmoid ------------
__global__ void final_kernel(
    const float* __restrict__ h2, const float* __restrict__ w3,
    const float* __restrict__ b3, const float* __restrict__ proto,
    const float* __restrict__ khw, const float* __restrict__ khb,
    float* __restrict__ out) {
  const int m = threadIdx.x;  // 64 lanes
  const float* h = h2 + m * 84;
  float z = b3[0];
  for (int k = 0; k < 84; ++k) z = fmaf(h[k], w3[k], z);
  float logit = khb[0];
#pragma unroll
  for (int p = 0; p < 10; ++p) {
    const float c = cosf((z - proto[p]) * 0.5f);
    const float c2 = c * c;
    logit = fmaf(c2 * c2, khw[p], logit);
  }
  const float pr = 1.0f / (1.0f + expf(-logit));
  out[m * 2 + 0] = pr;
  out[m * 2 + 1] = 1.0f - pr;
}

// ---------------------------------------------------------------------------
extern "C" void kernel_launch(void* const* d_in, const int* in_sizes, int n_in,
                              void* d_out, int out_size, void* d_ws, size_t ws_size,
                              hipStream_t stream) {
  const float* x    = (const float*)d_in[0];
  const float* w1   = (const float*)d_in[1];
  const float* b1   = (const float*)d_in[2];
  const float* w2   = (const float*)d_in[3];
  const float* b2   = (const float*)d_in[4];
  const float* fw1  = (const float*)d_in[5];
  const float* fb1  = (const float*)d_in[6];
  const float* fw2  = (const float*)d_in[7];
  const float* fb2  = (const float*)d_in[8];
  const float* fw3  = (const float*)d_in[9];
  const float* fb3  = (const float*)d_in[10];
  const float* prot = (const float*)d_in[11];
  const float* khw  = (const float*)d_in[12];
  const float* khb  = (const float*)d_in[13];
  float* out = (float*)d_out;

  float* ws = (float*)d_ws;
  // pool1 (dead after conv2) is aliased by fc1 partials (written after).
  float* pool1 = ws;                           // 64*123*123*6 = 5,809,536 f
  float* part  = ws;                           // 437*7680     = 3,356,160 f (alias)
  float* A     = ws + 5809536;                 // 64*55872     = 3,575,808 f
  float* h1    = A + 3575808;                  // 7680 f
  float* h2    = h1 + 7680;                    // 5376 f

  conv1_pool <<<dim3(18, 64), 256, 0, stream>>>(x, w1, b1, pool1);
  conv2_pool <<<dim3(25, 64), 256, 0, stream>>>(pool1, w2, b2, A);
  fc1_partial<<<dim3(NCHUNK), 256, 0, stream>>>(A, fw1, part);
  fc1_reduce <<<dim3(240), 256, 0, stream>>>(part, fb1, h1);
  fc2_kernel <<<dim3(21), 256, 0, stream>>>(h1, fw2, fb2, h2);
  final_kernel<<<dim3(1), 64, 0, stream>>>(h2, fw3, fb3, prot, khw, khb, out);
}